// Round 4
// baseline (908.398 us; speedup 1.0000x reference)
//
#include <hip/hip_runtime.h>
#include <hip/hip_cooperative_groups.h>
namespace cg = cooperative_groups;

#define BN 64
#define TN 1024
#define VN 1024
#define UNITSN 512
#define TWO_PI 6.283185307179586476925286766559f
#define GRID_BLOCKS 2048
#define BLK 256

// ---------------- fused cooperative kernel ----------------
// phase1: s[b*1024+tau] = sum_v x[b,tau,v]          (wave per row, 8 rows/wave)
// phase2: g[b*1024+tau] = sum_k (Br+iBi)[b,k]*s[k,tau]
// phase3: W[b*512+t]    = (1/2048)*sum_tau g[b,tau]*e^{-2pi i tau t/1024}
// phase4: out[b][j][t][{re,im}] = W[b,t] + (t+j>=511 ? W[b,t+j-511] : 0)
__global__ __launch_bounds__(BLK, 8)
void k_fused(const float* __restrict__ x, const float* __restrict__ Br,
             const float* __restrict__ Bi, float* __restrict__ ws0,
             float2* __restrict__ g, float4* __restrict__ out) {
    cg::grid_group grid = cg::this_grid();
    int tid    = threadIdx.x;
    int lane   = tid & 63;
    int waveId = blockIdx.x * 4 + (tid >> 6);          // 0..8191

    float* s = ws0;                                    // 65536 f32 = 256 KB

    // ---- phase 1: row reduce (concurrent waves cover contiguous 32MB slabs)
    for (int i = 0; i < 8; ++i) {
        int row = i * 8192 + waveId;
        const float4* xr = reinterpret_cast<const float4*>(x) + (size_t)row * (VN / 4);
        float acc = 0.f;
#pragma unroll
        for (int c = 0; c < 4; ++c) {
            float4 v = xr[c * 64 + lane];
            acc += (v.x + v.y) + (v.z + v.w);
        }
#pragma unroll
        for (int off = 32; off > 0; off >>= 1)
            acc += __shfl_down(acc, off, 64);
        if (lane == 0) s[row] = acc;
    }
    grid.sync();

    // ---- phase 2: g = Bm @ s  (thread per (b,tau); blocks 0..255 active)
    {
        int idx = blockIdx.x * BLK + tid;
        if (idx < BN * TN) {
            int b = idx >> 10, tau = idx & 1023;
            const float* brp = Br + b * 64;
            const float* bip = Bi + b * 64;
            float gr = 0.f, gi = 0.f;
#pragma unroll 8
            for (int k = 0; k < 64; ++k) {
                float sv = s[k * TN + tau];            // coalesced, L2-resident
                gr = fmaf(brp[k], sv, gr);
                gi = fmaf(bip[k], sv, gi);
            }
            g[idx] = make_float2(gr, gi);
        }
    }
    grid.sync();

    // ---- phase 3: DFT of g, wave per (b,t), 4 per wave (s space reused for W)
    float2* W = reinterpret_cast<float2*>(ws0);        // 32768 cplx = 256 KB
    for (int it = 0; it < 4; ++it) {
        int w = it * 8192 + waveId;                    // 0..32767
        int b = w >> 9, t = w & 511;
        const float2* gb = g + b * TN;
        int p0 = (lane * t) & 1023;
        int ps = (64 * t) & 1023;
        float cr, ci, c1, s1;
        sincosf((-TWO_PI / 1024.0f) * (float)p0, &ci, &cr);
        sincosf((-TWO_PI / 1024.0f) * (float)ps, &s1, &c1);
        float ar = 0.f, ai = 0.f;
#pragma unroll
        for (int i = 0; i < 16; ++i) {
            float2 gv = gb[lane + 64 * i];
            ar = fmaf(gv.x, cr, ar); ar = fmaf(-gv.y, ci, ar);
            ai = fmaf(gv.x, ci, ai); ai = fmaf(gv.y, cr, ai);
            float nr = cr * c1 - ci * s1;              // rotate twiddle
            float nc = cr * s1 + ci * c1;
            cr = nr; ci = nc;
        }
#pragma unroll
        for (int off = 32; off > 0; off >>= 1) {
            ar += __shfl_xor(ar, off, 64);
            ai += __shfl_xor(ai, off, 64);
        }
        if (lane == 0) W[w] = make_float2(ar * (1.0f / 2048.0f), ai * (1.0f / 2048.0f));
    }
    grid.sync();

    // ---- phase 4: expand + write output (grid-stride, float4 per thread-iter)
    for (int it = 0; it < 16; ++it) {
        int idx = it * (GRID_BLOCKS * BLK) + blockIdx.x * BLK + tid;
        int t2 = (idx & 255) * 2;
        int j  = (idx >> 8) & 511;
        int b  = idx >> 17;
        const float2* Wb = W + b * UNITSN;
        float4 w01 = *reinterpret_cast<const float4*>(Wb + t2);
        int k0 = t2 + j - 511;
        float2 z0 = (k0 >= 0)     ? Wb[k0]     : make_float2(0.f, 0.f);
        float2 z1 = (k0 + 1 >= 0) ? Wb[k0 + 1] : make_float2(0.f, 0.f);
        out[idx] = make_float4(w01.x + z0.x, w01.y + z0.y, w01.z + z1.x, w01.w + z1.y);
    }
}

// ---------------- fallback: R2's verified 4-kernel path ----------------
__global__ void k_reduce_v(const float* __restrict__ x, float* __restrict__ s) {
    int row  = blockIdx.x * 4 + (threadIdx.x >> 6);
    int lane = threadIdx.x & 63;
    const float4* xr = reinterpret_cast<const float4*>(x) + (size_t)row * (VN / 4);
    float acc = 0.f;
#pragma unroll
    for (int i = 0; i < 4; ++i) {
        float4 v = xr[i * 64 + lane];
        acc += (v.x + v.y) + (v.z + v.w);
    }
#pragma unroll
    for (int off = 32; off > 0; off >>= 1) acc += __shfl_down(acc, off, 64);
    if (lane == 0) s[row] = acc;
}

__global__ void k_dft(const float* __restrict__ s, float2* __restrict__ F) {
    int w    = (blockIdx.x * blockDim.x + threadIdx.x) >> 6;
    int lane = threadIdx.x & 63;
    int b    = w >> 9;
    int t    = w & 511;
    const float* sb = s + b * TN;
    int p0 = (lane * t) & 1023;
    int ps = (64 * t) & 1023;
    float cr, ci, c1, s1;
    sincosf((-TWO_PI / 1024.0f) * (float)p0, &ci, &cr);
    sincosf((-TWO_PI / 1024.0f) * (float)ps, &s1, &c1);
    float ar = 0.f, ai = 0.f;
#pragma unroll
    for (int i = 0; i < 16; ++i) {
        float sv = sb[lane + 64 * i];
        ar = fmaf(sv, cr, ar);
        ai = fmaf(sv, ci, ai);
        float nr = cr * c1 - ci * s1;
        float nc = cr * s1 + ci * c1;
        cr = nr; ci = nc;
    }
#pragma unroll
    for (int off = 32; off > 0; off >>= 1) {
        ar += __shfl_xor(ar, off, 64);
        ai += __shfl_xor(ai, off, 64);
    }
    if (lane == 0) F[b * UNITSN + t] = make_float2(ar, ai);
}

__global__ void k_matmul(const float* __restrict__ Br, const float* __restrict__ Bi,
                         const float2* __restrict__ F, float2* __restrict__ W) {
    int idx = blockIdx.x * blockDim.x + threadIdx.x;
    int b = idx >> 9;
    int t = idx & 511;
    float wr = 0.f, wi = 0.f;
#pragma unroll 16
    for (int k = 0; k < 64; ++k) {
        float br = Br[b * 64 + k];
        float bi = Bi[b * 64 + k];
        float2 f = F[k * UNITSN + t];
        wr += br * f.x - bi * f.y;
        wi += br * f.y + bi * f.x;
    }
    const float coef = 1.0f / 2048.0f;
    W[idx] = make_float2(wr * coef, wi * coef);
}

__global__ void k_expand(const float2* __restrict__ W, float4* __restrict__ out) {
    int idx = blockIdx.x * 256 + threadIdx.x;
    int t2 = (idx & 255) * 2;
    int j  = (idx >> 8) & 511;
    int b  = idx >> 17;
    const float2* Wb = W + b * UNITSN;
    float4 w01 = *reinterpret_cast<const float4*>(Wb + t2);
    int k0 = t2 + j - 511;
    float2 z0 = (k0 >= 0)     ? Wb[k0]     : make_float2(0.f, 0.f);
    float2 z1 = (k0 + 1 >= 0) ? Wb[k0 + 1] : make_float2(0.f, 0.f);
    out[idx] = make_float4(w01.x + z0.x, w01.y + z0.y, w01.z + z1.x, w01.w + z1.y);
}

extern "C" void kernel_launch(void* const* d_in, const int* in_sizes, int n_in,
                              void* d_out, int out_size, void* d_ws, size_t ws_size,
                              hipStream_t stream) {
    const float* x  = (const float*)d_in[0];
    // d_in[1], d_in[2] (A_r, A_i) provably unused: state column 0 stays zero.
    const float* Br = (const float*)d_in[3];
    const float* Bi = (const float*)d_in[4];

    char* ws = (char*)d_ws;
    float*  s_or_W = (float*)ws;                       // 256 KB (s, later W)
    float2* g      = (float2*)(ws + 256 * 1024);       // 512 KB

    void* args[] = {(void*)&x, (void*)&Br, (void*)&Bi,
                    (void*)&s_or_W, (void*)&g, (void*)&d_out};
    hipError_t err = hipLaunchCooperativeKernel((const void*)k_fused,
                                                dim3(GRID_BLOCKS), dim3(BLK),
                                                args, 0, stream);
    if (err != hipSuccess) {
        // fallback: R2's 4-kernel path (same ws layout: s at 0, F=g slot, W after)
        float*  s = (float*)ws;
        float2* F = (float2*)(ws + 256 * 1024);
        float2* W = (float2*)(ws + 256 * 1024 + 512 * 1024);
        k_reduce_v<<<BN * TN / 4, 256, 0, stream>>>(x, s);
        k_dft<<<(BN * UNITSN) / 4, 256, 0, stream>>>(s, F);
        k_matmul<<<(BN * UNITSN) / 256, 256, 0, stream>>>(Br, Bi, F, W);
        k_expand<<<(BN * UNITSN * (UNITSN / 2)) / 256, 256, 0, stream>>>(W, (float4*)d_out);
    }
}

// Round 5
// 99.043 us; speedup vs baseline: 9.1718x; 9.1718x over previous
//
#include <hip/hip_runtime.h>

#define BN 64
#define TN 1024
#define VN 1024
#define UNITSN 512
#define TWO_PI 6.283185307179586476925286766559f

// K1: s[b*1024+tau] = sum_v x[b, tau, v].  One wave (64 lanes) per row of 1024 floats.
__global__ void k_reduce_v(const float* __restrict__ x, float* __restrict__ s) {
    int row  = blockIdx.x * 4 + (threadIdx.x >> 6);   // 4 waves per 256-thread block
    int lane = threadIdx.x & 63;
    const float4* xr = reinterpret_cast<const float4*>(x) + (size_t)row * (VN / 4);
    float acc = 0.f;
#pragma unroll
    for (int i = 0; i < 4; ++i) {
        float4 v = xr[i * 64 + lane];                 // consecutive lanes -> consecutive 16B
        acc += (v.x + v.y) + (v.z + v.w);
    }
#pragma unroll
    for (int off = 32; off > 0; off >>= 1)
        acc += __shfl_down(acc, off, 64);
    if (lane == 0) s[row] = acc;
}

// K2: F[b*512+t] = sum_tau s[b,tau] * e^{-2*pi*i*tau*t/1024}, t in [0,512)
// One WAVE per (b,t). Lane l covers tau = l, l+64, ..., l+960 (16 steps).
// Twiddle computed DIRECTLY per step from integer phase via hw v_sin/v_cos:
// no libm sincosf, no serial rotation chain -> full ILP across the 16 steps.
__global__ void k_dft(const float* __restrict__ s, float2* __restrict__ F) {
    int w    = (blockIdx.x * blockDim.x + threadIdx.x) >> 6;  // global wave id
    int lane = threadIdx.x & 63;
    int b    = w >> 9;
    int t    = w & 511;
    const float* sb = s + b * TN;

    int p  = (lane * t) & 1023;        // phase index tau*t mod 1024
    int st = (64 * t) & 1023;          // per-step phase increment

    float ar = 0.f, ai = 0.f;
#pragma unroll
    for (int i = 0; i < 16; ++i) {
        float sv  = sb[lane + 64 * i];
        float ang = (float)p * (-TWO_PI / 1024.0f);
        float c   = __cosf(ang);       // v_cos_f32 (arg scaled by 1/2pi inline const)
        float n   = __sinf(ang);       // v_sin_f32
        ar = fmaf(sv, c, ar);
        ai = fmaf(sv, n, ai);
        p  = (p + st) & 1023;          // 1-cycle int update, not an fp chain
    }
#pragma unroll
    for (int off = 32; off > 0; off >>= 1) {
        ar += __shfl_xor(ar, off, 64);
        ai += __shfl_xor(ai, off, 64);
    }
    if (lane == 0) F[b * UNITSN + t] = make_float2(ar, ai);
}

// K3: W[b,t] = (1/2048) * sum_k (Br[b,k] + i*Bi[b,k]) * F[k,t]
// Wave = 16 t-values x 4 k-segments (16 k's each); shuffle-combine the 4 partials.
// 4x the waves of a thread-per-output layout -> hides L2 latency.
__global__ void k_matmul(const float* __restrict__ Br, const float* __restrict__ Bi,
                         const float2* __restrict__ F, float2* __restrict__ W) {
    int tid   = threadIdx.x;
    int lane  = tid & 63;
    int wv    = tid >> 6;                                  // wave in block, 0..3
    int b     = blockIdx.x >> 3;
    int tbase = ((blockIdx.x & 7) * 4 + wv) * 16;          // 16 consecutive t per wave
    int t     = tbase + (lane & 15);
    int seg   = lane >> 4;                                 // 0..3
    const float* brp = Br + b * 64 + seg * 16;
    const float* bip = Bi + b * 64 + seg * 16;
    float wr = 0.f, wi = 0.f;
#pragma unroll
    for (int i = 0; i < 16; ++i) {
        float br = brp[i];
        float bi = bip[i];
        float2 f = F[(seg * 16 + i) * UNITSN + t];         // 4x128B segments per instr
        wr = fmaf(br, f.x, wr); wr = fmaf(-bi, f.y, wr);
        wi = fmaf(br, f.y, wi); wi = fmaf(bi, f.x, wi);
    }
    wr += __shfl_xor(wr, 16, 64); wi += __shfl_xor(wi, 16, 64);
    wr += __shfl_xor(wr, 32, 64); wi += __shfl_xor(wi, 32, 64);
    if (seg == 0) {
        const float coef = 1.0f / 2048.0f;
        W[b * UNITSN + t] = make_float2(wr * coef, wi * coef);
    }
}

// K4: out[b][j][t][{re,im}] = W[b,t] + (t+j-511 >= 0 ? W[b, t+j-511] : 0)
// One thread writes 2 consecutive t's as a float4.
__global__ void k_expand(const float2* __restrict__ W, float4* __restrict__ out) {
    int idx = blockIdx.x * 256 + threadIdx.x;         // 64*512*256 total
    int t2 = (idx & 255) * 2;
    int j  = (idx >> 8) & 511;
    int b  = idx >> 17;
    const float2* Wb = W + b * UNITSN;
    float4 w01 = *reinterpret_cast<const float4*>(Wb + t2);  // W[t2], W[t2+1]
    int k0 = t2 + j - 511;
    float2 z0 = (k0 >= 0)     ? Wb[k0]     : make_float2(0.f, 0.f);
    float2 z1 = (k0 + 1 >= 0) ? Wb[k0 + 1] : make_float2(0.f, 0.f);
    out[idx] = make_float4(w01.x + z0.x, w01.y + z0.y, w01.z + z1.x, w01.w + z1.y);
}

extern "C" void kernel_launch(void* const* d_in, const int* in_sizes, int n_in,
                              void* d_out, int out_size, void* d_ws, size_t ws_size,
                              hipStream_t stream) {
    const float* x  = (const float*)d_in[0];
    // d_in[1], d_in[2] (A_r, A_i) are provably unused: the shift-register state's
    // column 0 stays zero for all 512 scan steps.
    const float* Br = (const float*)d_in[3];
    const float* Bi = (const float*)d_in[4];

    char* ws = (char*)d_ws;
    float*  s = (float*)ws;                       // 64*1024 f32 = 256 KB
    float2* F = (float2*)(ws + 256 * 1024);       // 64*512 cplx = 256 KB
    float2* W = (float2*)(ws + 512 * 1024);       // 64*512 cplx = 256 KB

    // K1: 65536 rows, 4 rows/block
    k_reduce_v<<<BN * TN / 4, 256, 0, stream>>>(x, s);
    // K2: 64 b * 512 t waves, 4 waves/block
    k_dft<<<(BN * UNITSN) / 4, 256, 0, stream>>>(s, F);
    // K3: 64 b * 8 t-chunks (wave = 16t x 4seg)
    k_matmul<<<BN * 8, 256, 0, stream>>>(Br, Bi, F, W);
    // K4: 64*512*256 threads
    k_expand<<<(BN * UNITSN * (UNITSN / 2)) / 256, 256, 0, stream>>>(W, (float4*)d_out);
}